// Round 1
// baseline (339.038 us; speedup 1.0000x reference)
//
#include <hip/hip_runtime.h>
#include <math.h>

#define GAIN_CAP 0.99f
#define EPSV 1e-4f

static constexpr int B = 4, C = 128, H = 256, W = 256, O = 16, M = 32;
static constexpr int HW = H * W;

// ws layout (floats):
//   [0, SF_SZ)            : steer fields sf[b][p][hw], p=0..2
//   [SF_SZ, +G_SZ)        : gains g[b][c][p] (post first clamp)
//   [SF_SZ+G_SZ, +C*3)    : inv denominators inv[c][p]
static constexpr int SF_SZ = B * 3 * HW;
static constexpr int G_SZ  = B * C * 3;

__device__ __forceinline__ float softplusf(float x) {
    // numerically stable, matches jax.nn.softplus: log1p(exp(-|x|)) + max(x,0)
    return log1pf(expf(-fabsf(x))) + fmaxf(x, 0.0f);
}
__device__ __forceinline__ float clampg(float v) {
    // GAIN_CAP - relu(GAIN_CAP - relu(v)) == clamp(v, 0, GAIN_CAP)
    return fminf(fmaxf(v, 0.0f), GAIN_CAP);
}

// One block, 512 threads: thread t = (b, c). All transcendentals live here.
__global__ void setup_kernel(const float* __restrict__ r_center,
                             const float* __restrict__ r_h,
                             const float* __restrict__ r_v,
                             const float* __restrict__ r_d,
                             const float* __restrict__ g_h,
                             const float* __restrict__ g_v,
                             const float* __restrict__ g_d,
                             const float* __restrict__ modulation, // [B,M]
                             const float* __restrict__ mod_w,      // [3,M]
                             float* __restrict__ gains,            // [B,C,3]
                             float* __restrict__ invd)             // [C,3]
{
    int t = threadIdx.x;          // 0..511
    int b = t >> 7;               // /C
    int c = t & (C - 1);

    float rc = softplusf(r_center[c]) + EPSV;
    float dh = rc + softplusf(r_h[c]) + EPSV;
    float dv = rc + softplusf(r_v[c]) + EPSV;
    float dd = 2.0f * (rc + softplusf(r_d[c]) + EPSV);
    if (b == 0) {
        invd[c * 3 + 0] = 1.0f / dh;
        invd[c * 3 + 1] = 1.0f / dv;
        invd[c * 3 + 2] = 1.0f / dd;
    }

    // delta[b][p] = tanh(modulation[b,:] . mod_w[p,:])
    float a0 = 0.f, a1 = 0.f, a2 = 0.f;
#pragma unroll
    for (int m = 0; m < M; ++m) {
        float mv = modulation[b * M + m];
        a0 += mv * mod_w[0 * M + m];
        a1 += mv * mod_w[1 * M + m];
        a2 += mv * mod_w[2 * M + m];
    }
    float d0 = tanhf(a0), d1 = tanhf(a1), d2 = tanhf(a2);

    gains[(b * C + c) * 3 + 0] = clampg(tanhf(g_h[c]) * (1.0f + 0.1f * d0));
    gains[(b * C + c) * 3 + 1] = clampg(tanhf(g_v[c]) * (1.0f + 0.1f * d1));
    gains[(b * C + c) * 3 + 2] = clampg(tanhf(g_d[c]) * (1.0f + 0.1f * d2));
}

// steer fields: [B,3,HW] = tanh(1x1 conv over O=16). Shared across all C.
__global__ void steer_kernel(const float* __restrict__ steer,   // [B,O,HW]
                             const float* __restrict__ steer_w, // [4,O]
                             float* __restrict__ sf)            // [B,3,HW]
{
    int idx = blockIdx.x * blockDim.x + threadIdx.x; // b*HW + hw
    int b  = idx >> 16;        // / HW
    int hw = idx & (HW - 1);

    const float* sp = steer + (size_t)b * O * HW + hw;
    float a0 = 0.f, a1 = 0.f, a2 = 0.f;
#pragma unroll
    for (int o = 0; o < O; ++o) {
        float v = sp[(size_t)o * HW];
        a0 += v * steer_w[0 * O + o];
        a1 += v * steer_w[1 * O + o];
        a2 += v * steer_w[2 * O + o];
    }
    sf[(size_t)(b * 3 + 0) * HW + hw] = tanhf(a0);
    sf[(size_t)(b * 3 + 1) * HW + hw] = tanhf(a1);
    sf[(size_t)(b * 3 + 2) * HW + hw] = tanhf(a2);
}

// Hot kernel: 9-point periodic stencil + precomputed gains/fields.
__global__ void __launch_bounds__(256)
main_kernel(const float* __restrict__ x,     // [B,C,H,W]
            const float* __restrict__ sf,    // [B,3,HW]
            const float* __restrict__ gains, // [B,C,3]
            const float* __restrict__ invd,  // [C,3]
            float* __restrict__ out)
{
    int idx = blockIdx.x * 256 + threadIdx.x;
    int w  = idx & (W - 1);
    int h  = (idx >> 8) & (H - 1);
    int bc = idx >> 16;            // b*C + c  (uniform per block)
    int c  = bc & (C - 1);
    int b  = bc >> 7;

    const float* plane = x + (size_t)bc * HW;
    int wp = (w + 1) & (W - 1), wm = (w - 1) & (W - 1);
    int hp = (h + 1) & (H - 1), hm = (h - 1) & (H - 1);
    const float* row_c = plane + h  * W;
    const float* row_u = plane + hm * W;
    const float* row_d = plane + hp * W;

    float center = row_c[w];
    float right  = row_c[wp], left = row_c[wm];
    float up     = row_u[w],  down = row_d[w];
    float ne = row_d[wp], sw = row_u[wm], nw = row_u[wp], se = row_d[wm];

    float fh = (right + left - 2.0f * center) * invd[c * 3 + 0];
    float fv = (up + down - 2.0f * center)    * invd[c * 3 + 1];
    float fd = (ne + sw + nw + se - 4.0f * center) * invd[c * 3 + 2];

    int hw = (h << 8) | w;
    float s0 = sf[(size_t)(b * 3 + 0) * HW + hw];
    float s1 = sf[(size_t)(b * 3 + 1) * HW + hw];
    float s2 = sf[(size_t)(b * 3 + 2) * HW + hw];

    float gh = clampg(gains[bc * 3 + 0] * (1.0f + 0.2f * s0));
    float gv = clampg(gains[bc * 3 + 1] * (1.0f + 0.2f * s1));
    float gd = clampg(gains[bc * 3 + 2] * (1.0f + 0.2f * s2));

    out[idx] = center + gh * fh + gv * fv + gd * fd;
}

extern "C" void kernel_launch(void* const* d_in, const int* in_sizes, int n_in,
                              void* d_out, int out_size, void* d_ws, size_t ws_size,
                              hipStream_t stream) {
    const float* x          = (const float*)d_in[0];
    const float* steer      = (const float*)d_in[1];
    const float* modulation = (const float*)d_in[2];
    const float* r_center   = (const float*)d_in[3];
    const float* r_horiz    = (const float*)d_in[4];
    const float* r_vert     = (const float*)d_in[5];
    const float* r_diag     = (const float*)d_in[6];
    const float* g_horiz    = (const float*)d_in[7];
    const float* g_vert     = (const float*)d_in[8];
    const float* g_diag     = (const float*)d_in[9];
    const float* steer_w    = (const float*)d_in[10];
    const float* mod_w      = (const float*)d_in[11];

    float* ws    = (float*)d_ws;
    float* sf    = ws;
    float* gains = ws + SF_SZ;
    float* invd  = gains + G_SZ;
    float* out   = (float*)d_out;

    setup_kernel<<<1, B * C, 0, stream>>>(r_center, r_horiz, r_vert, r_diag,
                                          g_horiz, g_vert, g_diag,
                                          modulation, mod_w, gains, invd);
    steer_kernel<<<(B * HW) / 256, 256, 0, stream>>>(steer, steer_w, sf);
    main_kernel<<<(B * C * HW) / 256, 256, 0, stream>>>(x, sf, gains, invd, out);
}

// Round 3
// 284.229 us; speedup vs baseline: 1.1928x; 1.1928x over previous
//
#include <hip/hip_runtime.h>
#include <math.h>

#define GAIN_CAP 0.99f
#define EPSV 1e-4f

static constexpr int B = 4, C = 128, H = 256, W = 256, O = 16, M = 32;
static constexpr int HW = H * W;

typedef float vfloat4 __attribute__((ext_vector_type(4)));  // clang-native for nontemporal builtin

// ws layout (floats): sf[B][3][HW], gains[B][C][3], invd[C][3]
static constexpr int SF_SZ = B * 3 * HW;
static constexpr int G_SZ  = B * C * 3;

__device__ __forceinline__ float softplusf(float x) {
    return log1pf(expf(-fabsf(x))) + fmaxf(x, 0.0f);
}
__device__ __forceinline__ float clampg(float v) {
    return fminf(fmaxf(v, 0.0f), GAIN_CAP);
}

// steer fields (vectorized) + per-(b,c) gain / per-c denominator setup in block 0.
__global__ void __launch_bounds__(256)
steer_kernel(const float* __restrict__ steer,   // [B,O,HW]
             const float* __restrict__ steer_w, // [4,O]
             const float* __restrict__ r_center,
             const float* __restrict__ r_h,
             const float* __restrict__ r_v,
             const float* __restrict__ r_d,
             const float* __restrict__ g_h,
             const float* __restrict__ g_v,
             const float* __restrict__ g_d,
             const float* __restrict__ modulation, // [B,M]
             const float* __restrict__ mod_w,      // [3,M]
             float* __restrict__ sf,               // [B,3,HW]
             float* __restrict__ gains,            // [B,C,3]
             float* __restrict__ invd)             // [C,3]
{
    // ---- tiny setup work, block 0 only (128 threads active) ----
    if (blockIdx.x == 0 && threadIdx.x < C) {
        int c = threadIdx.x;
        float rc = softplusf(r_center[c]) + EPSV;
        invd[c * 3 + 0] = 1.0f / (rc + softplusf(r_h[c]) + EPSV);
        invd[c * 3 + 1] = 1.0f / (rc + softplusf(r_v[c]) + EPSV);
        invd[c * 3 + 2] = 1.0f / (2.0f * (rc + softplusf(r_d[c]) + EPSV));
        float th = tanhf(g_h[c]), tv = tanhf(g_v[c]), td = tanhf(g_d[c]);
        for (int b = 0; b < B; ++b) {
            float a0 = 0.f, a1 = 0.f, a2 = 0.f;
#pragma unroll
            for (int m = 0; m < M; ++m) {
                float mv = modulation[b * M + m];
                a0 += mv * mod_w[0 * M + m];
                a1 += mv * mod_w[1 * M + m];
                a2 += mv * mod_w[2 * M + m];
            }
            gains[(b * C + c) * 3 + 0] = clampg(th * (1.0f + 0.1f * tanhf(a0)));
            gains[(b * C + c) * 3 + 1] = clampg(tv * (1.0f + 0.1f * tanhf(a1)));
            gains[(b * C + c) * 3 + 2] = clampg(td * (1.0f + 0.1f * tanhf(a2)));
        }
    }

    // ---- steer fields: 4 pixels per thread ----
    int idx = blockIdx.x * 256 + threadIdx.x;   // 0 .. B*HW/4-1
    int b   = idx >> 14;                        // / (HW/4)
    int hw4 = idx & 16383;
    const float4* sp = (const float4*)(steer + ((size_t)b * O << 16)) + hw4;

    float4 a0 = {0,0,0,0}, a1 = {0,0,0,0}, a2 = {0,0,0,0};
#pragma unroll
    for (int o = 0; o < O; ++o) {
        float4 v = sp[(size_t)o << 14];
        float w0 = steer_w[o], w1 = steer_w[O + o], w2 = steer_w[2 * O + o];
        a0.x += v.x * w0; a0.y += v.y * w0; a0.z += v.z * w0; a0.w += v.w * w0;
        a1.x += v.x * w1; a1.y += v.y * w1; a1.z += v.z * w1; a1.w += v.w * w1;
        a2.x += v.x * w2; a2.y += v.y * w2; a2.z += v.z * w2; a2.w += v.w * w2;
    }
    float4* o0 = (float4*)(sf + ((size_t)(b * 3 + 0) << 16)) + hw4;
    float4* o1 = (float4*)(sf + ((size_t)(b * 3 + 1) << 16)) + hw4;
    float4* o2 = (float4*)(sf + ((size_t)(b * 3 + 2) << 16)) + hw4;
    *o0 = make_float4(tanhf(a0.x), tanhf(a0.y), tanhf(a0.z), tanhf(a0.w));
    *o1 = make_float4(tanhf(a1.x), tanhf(a1.y), tanhf(a1.z), tanhf(a1.w));
    *o2 = make_float4(tanhf(a2.x), tanhf(a2.y), tanhf(a2.z), tanhf(a2.w));
}

// Hot kernel: one wave == one full row (64 lanes x float4 == W=256).
// Each wave strip-mines 16 rows, rotating up/center/down rows in registers.
// Horizontal neighbors: register picks + 2 shuffles per row (periodic in-wave).
__global__ void __launch_bounds__(256)
main_kernel(const float* __restrict__ x,     // [B,C,H,W]
            const float* __restrict__ sf,    // [B,3,HW]
            const float* __restrict__ gains, // [B,C,3]
            const float* __restrict__ invd,  // [C,3]
            float* __restrict__ out)
{
    constexpr int RPW = 16;                 // rows per wave
    int lane  = threadIdx.x & 63;
    int wave  = threadIdx.x >> 6;
    int strip = blockIdx.x & 3;             // 4 blocks per plane
    int bc    = blockIdx.x >> 2;            // b*C + c
    int c     = bc & (C - 1);
    int b     = bc >> 7;
    int h0    = strip * 64 + wave * RPW;

    const float* plane = x + ((size_t)bc << 16);
    const float* sfb0  = sf + ((size_t)(b * 3 + 0) << 16);
    const float* sfb1  = sf + ((size_t)(b * 3 + 1) << 16);
    const float* sfb2  = sf + ((size_t)(b * 3 + 2) << 16);
    float*       outp  = out + ((size_t)bc << 16);

    float ih  = invd[c * 3 + 0], iv = invd[c * 3 + 1], idg = invd[c * 3 + 2];
    float g0  = gains[bc * 3 + 0], g1 = gains[bc * 3 + 1], g2 = gains[bc * 3 + 2];

    int lp = (lane + 1) & 63, lm = (lane - 1) & 63;

    float4 u4 = ((const float4*)(plane + (((h0 - 1) & 255) << 8)))[lane];
    float4 c4 = ((const float4*)(plane + (h0 << 8)))[lane];
    float uRe = __shfl(u4.x, lp), uLe = __shfl(u4.w, lm);
    float cRe = __shfl(c4.x, lp), cLe = __shfl(c4.w, lm);

    for (int r = 0; r < RPW; ++r) {
        int h  = h0 + r;
        int hd = (h + 1) & 255;
        float4 d4 = ((const float4*)(plane + (hd << 8)))[lane];
        float4 s0 = ((const float4*)(sfb0 + (h << 8)))[lane];
        float4 s1 = ((const float4*)(sfb1 + (h << 8)))[lane];
        float4 s2 = ((const float4*)(sfb2 + (h << 8)))[lane];
        float dRe = __shfl(d4.x, lp), dLe = __shfl(d4.w, lm);

        float cA[4]  = {c4.x, c4.y, c4.z, c4.w};
        float uA[4]  = {u4.x, u4.y, u4.z, u4.w};
        float dA[4]  = {d4.x, d4.y, d4.z, d4.w};
        float crA[4] = {c4.y, c4.z, c4.w, cRe};
        float clA[4] = {cLe, c4.x, c4.y, c4.z};
        float urA[4] = {u4.y, u4.z, u4.w, uRe};
        float ulA[4] = {uLe, u4.x, u4.y, u4.z};
        float drA[4] = {d4.y, d4.z, d4.w, dRe};
        float dlA[4] = {dLe, d4.x, d4.y, d4.z};
        float sA0[4] = {s0.x, s0.y, s0.z, s0.w};
        float sA1[4] = {s1.x, s1.y, s1.z, s1.w};
        float sA2[4] = {s2.x, s2.y, s2.z, s2.w};

        float oA[4];
#pragma unroll
        for (int j = 0; j < 4; ++j) {
            float fh = (crA[j] + clA[j] - 2.0f * cA[j]) * ih;
            float fv = (uA[j] + dA[j] - 2.0f * cA[j]) * iv;
            float fd = (drA[j] + dlA[j] + urA[j] + ulA[j] - 4.0f * cA[j]) * idg;
            float gh = clampg(g0 * (1.0f + 0.2f * sA0[j]));
            float gv = clampg(g1 * (1.0f + 0.2f * sA1[j]));
            float gd = clampg(g2 * (1.0f + 0.2f * sA2[j]));
            oA[j] = cA[j] + gh * fh + gv * fv + gd * fd;
        }
        vfloat4 ov = {oA[0], oA[1], oA[2], oA[3]};
        __builtin_nontemporal_store(ov, (vfloat4*)(outp + (h << 8)) + lane);

        u4 = c4; uRe = cRe; uLe = cLe;
        c4 = d4; cRe = dRe; cLe = dLe;
    }
}

extern "C" void kernel_launch(void* const* d_in, const int* in_sizes, int n_in,
                              void* d_out, int out_size, void* d_ws, size_t ws_size,
                              hipStream_t stream) {
    const float* x          = (const float*)d_in[0];
    const float* steer      = (const float*)d_in[1];
    const float* modulation = (const float*)d_in[2];
    const float* r_center   = (const float*)d_in[3];
    const float* r_horiz    = (const float*)d_in[4];
    const float* r_vert     = (const float*)d_in[5];
    const float* r_diag     = (const float*)d_in[6];
    const float* g_horiz    = (const float*)d_in[7];
    const float* g_vert     = (const float*)d_in[8];
    const float* g_diag     = (const float*)d_in[9];
    const float* steer_w    = (const float*)d_in[10];
    const float* mod_w      = (const float*)d_in[11];

    float* ws    = (float*)d_ws;
    float* sf    = ws;
    float* gains = ws + SF_SZ;
    float* invd  = gains + G_SZ;
    float* out   = (float*)d_out;

    steer_kernel<<<(B * HW / 4) / 256, 256, 0, stream>>>(
        steer, steer_w, r_center, r_horiz, r_vert, r_diag,
        g_horiz, g_vert, g_diag, modulation, mod_w, sf, gains, invd);
    main_kernel<<<B * C * 4, 256, 0, stream>>>(x, sf, gains, invd, out);
}

// Round 4
// 272.554 us; speedup vs baseline: 1.2439x; 1.0428x over previous
//
#include <hip/hip_runtime.h>
#include <math.h>

#define GAIN_CAP 0.99f
#define EPSV 1e-4f

static constexpr int B = 4, C = 128, H = 256, W = 256, O = 16, M = 32;
static constexpr int HW = H * W;

typedef float   vfloat4 __attribute__((ext_vector_type(4)));
typedef _Float16 half4v __attribute__((ext_vector_type(4)));
typedef _Float16 half8v __attribute__((ext_vector_type(8)));

// ws layout: sfp[B][HW] as half4 (8 B/px) = 8 MB, then gains[B*C*3], invd[C*3]
static constexpr int SFP_FLOATS = B * HW * 2;   // half4 == 2 floats
static constexpr int G_SZ = B * C * 3;

__device__ __forceinline__ float softplusf(float x) {
    return log1pf(expf(-fabsf(x))) + fmaxf(x, 0.0f);
}
__device__ __forceinline__ float clampg(float v) {
    return fminf(fmaxf(v, 0.0f), GAIN_CAP);
}
__device__ __forceinline__ float fast_tanh(float x) {
    // tanh(x) = 1 - 2/(e^{2x}+1); __expf -> v_exp_f32, rcp -> v_rcp_f32.
    // x->+inf: e=inf -> 1; x->-inf: e=0 -> -1. No NaN paths.
    float e = __expf(2.0f * x);
    return 1.0f - 2.0f * __builtin_amdgcn_rcpf(e + 1.0f);
}

// steer fields -> packed half4 {s0,s1,s2,0}; per-(b,c) gains + invd in block 0.
__global__ void __launch_bounds__(256)
steer_kernel(const float* __restrict__ steer,   // [B,O,HW]
             const float* __restrict__ steer_w, // [4,O]
             const float* __restrict__ r_center,
             const float* __restrict__ r_h,
             const float* __restrict__ r_v,
             const float* __restrict__ r_d,
             const float* __restrict__ g_h,
             const float* __restrict__ g_v,
             const float* __restrict__ g_d,
             const float* __restrict__ modulation, // [B,M]
             const float* __restrict__ mod_w,      // [3,M]
             half4v* __restrict__ sfp,             // [B,HW]
             float* __restrict__ gains,            // [B,C,3]
             float* __restrict__ invd)             // [C,3]
{
    if (blockIdx.x == 0 && threadIdx.x < C) {
        int c = threadIdx.x;
        float rc = softplusf(r_center[c]) + EPSV;
        invd[c * 3 + 0] = 1.0f / (rc + softplusf(r_h[c]) + EPSV);
        invd[c * 3 + 1] = 1.0f / (rc + softplusf(r_v[c]) + EPSV);
        invd[c * 3 + 2] = 1.0f / (2.0f * (rc + softplusf(r_d[c]) + EPSV));
        float th = tanhf(g_h[c]), tv = tanhf(g_v[c]), td = tanhf(g_d[c]);
        for (int b = 0; b < B; ++b) {
            float a0 = 0.f, a1 = 0.f, a2 = 0.f;
#pragma unroll
            for (int m = 0; m < M; ++m) {
                float mv = modulation[b * M + m];
                a0 += mv * mod_w[0 * M + m];
                a1 += mv * mod_w[1 * M + m];
                a2 += mv * mod_w[2 * M + m];
            }
            gains[(b * C + c) * 3 + 0] = clampg(th * (1.0f + 0.1f * tanhf(a0)));
            gains[(b * C + c) * 3 + 1] = clampg(tv * (1.0f + 0.1f * tanhf(a1)));
            gains[(b * C + c) * 3 + 2] = clampg(td * (1.0f + 0.1f * tanhf(a2)));
        }
    }

    int idx = blockIdx.x * 256 + threadIdx.x;  // 0 .. B*HW-1  (1024 blocks)
    int b   = idx >> 16;
    int hw  = idx & 65535;
    const float* sp = steer + ((size_t)b * O << 16) + hw;

    float a0 = 0.f, a1 = 0.f, a2 = 0.f;
#pragma unroll
    for (int o = 0; o < O; ++o) {
        float v = sp[(size_t)o << 16];
        a0 += v * steer_w[o];
        a1 += v * steer_w[O + o];
        a2 += v * steer_w[2 * O + o];
    }
    half4v hv = { (_Float16)fast_tanh(a0), (_Float16)fast_tanh(a1),
                  (_Float16)fast_tanh(a2), (_Float16)0.f };
    sfp[idx] = hv;
}

__device__ __forceinline__ vfloat4 row_compute(
    const float4& u, const float4& cc, const float4& d,
    float uL, float uR, float cL, float cR, float dL, float dR,
    float ih, float iv, float idg, float g0, float g1, float g2,
    const float (&s0)[4], const float (&s1)[4], const float (&s2)[4])
{
    float cA[4]  = {cc.x, cc.y, cc.z, cc.w};
    float uA[4]  = {u.x, u.y, u.z, u.w};
    float dA[4]  = {d.x, d.y, d.z, d.w};
    float crA[4] = {cc.y, cc.z, cc.w, cR};
    float clA[4] = {cL, cc.x, cc.y, cc.z};
    float urA[4] = {u.y, u.z, u.w, uR};
    float ulA[4] = {uL, u.x, u.y, u.z};
    float drA[4] = {d.y, d.z, d.w, dR};
    float dlA[4] = {dL, d.x, d.y, d.z};
    vfloat4 o;
#pragma unroll
    for (int j = 0; j < 4; ++j) {
        float fh = (crA[j] + clA[j] - 2.0f * cA[j]) * ih;
        float fv = (uA[j] + dA[j] - 2.0f * cA[j]) * iv;
        float fd = (drA[j] + dlA[j] + urA[j] + ulA[j] - 4.0f * cA[j]) * idg;
        float gh = clampg(g0 * (1.0f + 0.2f * s0[j]));
        float gv = clampg(g1 * (1.0f + 0.2f * s1[j]));
        float gd = clampg(g2 * (1.0f + 0.2f * s2[j]));
        o[j] = cA[j] + gh * fh + gv * fv + gd * fd;
    }
    return o;
}

// One wave == one row (64 lanes x float4 == W). NCH=2 channels per block share
// sf rows; RPW=8 rows per wave; u/c/d rows rotate in registers.
__global__ void __launch_bounds__(256)
main_kernel(const float* __restrict__ x,      // [B,C,H,W]
            const half4v* __restrict__ sfp,   // [B,HW]
            const float* __restrict__ gains,  // [B,C,3]
            const float* __restrict__ invd,   // [C,3]
            float* __restrict__ out)
{
    constexpr int RPW = 8;
    int lane  = threadIdx.x & 63;
    int wave  = threadIdx.x >> 6;
    int gid   = blockIdx.x;
    int strip = gid & 7;            // 8 strips of 32 rows -> 8 XCDs
    int cg    = (gid >> 3) & 63;    // channel pair
    int b     = gid >> 9;
    int bc0   = b * C + cg * 2;
    int c0    = bc0 & (C - 1);
    int h0    = strip * 32 + wave * RPW;

    const float* p0 = x + ((size_t)bc0 << 16);
    const float* p1 = p0 + HW;
    float* q0 = out + ((size_t)bc0 << 16);
    float* q1 = q0 + HW;
    const half4v* sfb = sfp + ((size_t)b << 16);

    float ih0 = invd[c0 * 3 + 0], iv0 = invd[c0 * 3 + 1], id0 = invd[c0 * 3 + 2];
    float ih1 = invd[c0 * 3 + 3], iv1 = invd[c0 * 3 + 4], id1 = invd[c0 * 3 + 5];
    float g00 = gains[bc0 * 3 + 0], g01 = gains[bc0 * 3 + 1], g02 = gains[bc0 * 3 + 2];
    float g10 = gains[bc0 * 3 + 3], g11 = gains[bc0 * 3 + 4], g12 = gains[bc0 * 3 + 5];

    int lp = (lane + 1) & 63, lm = (lane - 1) & 63;
    int hm = (h0 - 1) & 255;

    float4 u0 = ((const float4*)(p0 + (hm << 8)))[lane];
    float4 u1 = ((const float4*)(p1 + (hm << 8)))[lane];
    float4 c0v = ((const float4*)(p0 + (h0 << 8)))[lane];
    float4 c1v = ((const float4*)(p1 + (h0 << 8)))[lane];
    float u0R = __shfl(u0.x, lp), u0L = __shfl(u0.w, lm);
    float u1R = __shfl(u1.x, lp), u1L = __shfl(u1.w, lm);
    float c0R = __shfl(c0v.x, lp), c0L = __shfl(c0v.w, lm);
    float c1R = __shfl(c1v.x, lp), c1L = __shfl(c1v.w, lm);

    for (int r = 0; r < RPW; ++r) {
        int h  = h0 + r;
        int hd = (h + 1) & 255;
        float4 d0 = ((const float4*)(p0 + (hd << 8)))[lane];
        float4 d1 = ((const float4*)(p1 + (hd << 8)))[lane];
        const float4* sro = (const float4*)(sfb + ((size_t)h << 8));
        float4 sA = sro[2 * lane], sB = sro[2 * lane + 1];

        float d0R = __shfl(d0.x, lp), d0L = __shfl(d0.w, lm);
        float d1R = __shfl(d1.x, lp), d1L = __shfl(d1.w, lm);

        half8v hA = __builtin_bit_cast(half8v, sA);
        half8v hB = __builtin_bit_cast(half8v, sB);
        float s0[4], s1[4], s2[4];
        s0[0] = (float)hA[0]; s1[0] = (float)hA[1]; s2[0] = (float)hA[2];
        s0[1] = (float)hA[4]; s1[1] = (float)hA[5]; s2[1] = (float)hA[6];
        s0[2] = (float)hB[0]; s1[2] = (float)hB[1]; s2[2] = (float)hB[2];
        s0[3] = (float)hB[4]; s1[3] = (float)hB[5]; s2[3] = (float)hB[6];

        vfloat4 o0 = row_compute(u0, c0v, d0, u0L, u0R, c0L, c0R, d0L, d0R,
                                 ih0, iv0, id0, g00, g01, g02, s0, s1, s2);
        vfloat4 o1 = row_compute(u1, c1v, d1, u1L, u1R, c1L, c1R, d1L, d1R,
                                 ih1, iv1, id1, g10, g11, g12, s0, s1, s2);
        __builtin_nontemporal_store(o0, (vfloat4*)(q0 + (h << 8)) + lane);
        __builtin_nontemporal_store(o1, (vfloat4*)(q1 + (h << 8)) + lane);

        u0 = c0v; u0R = c0R; u0L = c0L;
        u1 = c1v; u1R = c1R; u1L = c1L;
        c0v = d0; c0R = d0R; c0L = d0L;
        c1v = d1; c1R = d1R; c1L = d1L;
    }
}

extern "C" void kernel_launch(void* const* d_in, const int* in_sizes, int n_in,
                              void* d_out, int out_size, void* d_ws, size_t ws_size,
                              hipStream_t stream) {
    const float* x          = (const float*)d_in[0];
    const float* steer      = (const float*)d_in[1];
    const float* modulation = (const float*)d_in[2];
    const float* r_center   = (const float*)d_in[3];
    const float* r_horiz    = (const float*)d_in[4];
    const float* r_vert     = (const float*)d_in[5];
    const float* r_diag     = (const float*)d_in[6];
    const float* g_horiz    = (const float*)d_in[7];
    const float* g_vert     = (const float*)d_in[8];
    const float* g_diag     = (const float*)d_in[9];
    const float* steer_w    = (const float*)d_in[10];
    const float* mod_w      = (const float*)d_in[11];

    float* ws     = (float*)d_ws;
    half4v* sfp   = (half4v*)ws;
    float* gains  = ws + SFP_FLOATS;
    float* invd   = gains + G_SZ;
    float* out    = (float*)d_out;

    steer_kernel<<<(B * HW) / 256, 256, 0, stream>>>(
        steer, steer_w, r_center, r_horiz, r_vert, r_diag,
        g_horiz, g_vert, g_diag, modulation, mod_w, sfp, gains, invd);
    main_kernel<<<B * (C / 2) * 8, 256, 0, stream>>>(x, sfp, gains, invd, out);
}